// Round 1
// baseline (308.647 us; speedup 1.0000x reference)
//
#include <hip/hip_runtime.h>
#include <stdint.h>

#define B_ 2
#define S_ 2048
#define D_ 1024
#define H_ 16
#define DH_ 64
#define M_ 4096
#define LOG2E 1.44269504088896340736f

typedef __attribute__((ext_vector_type(8))) short short8;
typedef __attribute__((ext_vector_type(4))) float f32x4;

__device__ __forceinline__ unsigned short f2bf(float f) {
  union { float f; uint32_t u; } x; x.f = f;
  uint32_t u = x.u;
  u += 0x7FFFu + ((u >> 16) & 1u);
  return (unsigned short)(u >> 16);
}

__device__ __forceinline__ void gll16(const void* g, void* l) {
  __builtin_amdgcn_global_load_lds(
      (__attribute__((address_space(1))) void*)(g),
      (__attribute__((address_space(3))) void*)(l), 16, 0, 0);
}

// ---- f32 -> bf16 flat convert (4 elems/thread) ----
__global__ __launch_bounds__(256) void k_cvt(const float* __restrict__ in,
                                             unsigned short* __restrict__ out, int n4) {
  int i = blockIdx.x * 256 + threadIdx.x;
  if (i < n4) {
    float4 v = reinterpret_cast<const float4*>(in)[i];
    ushort4 o;
    o.x = f2bf(v.x); o.y = f2bf(v.y); o.z = f2bf(v.z); o.w = f2bf(v.w);
    reinterpret_cast<ushort4*>(out)[i] = o;
  }
}

// ---- W [K][N] f32 -> WT [N][K] bf16 (32x32 LDS tile) ----
__global__ __launch_bounds__(256) void k_cvt_t(const float* __restrict__ W,
                                               unsigned short* __restrict__ WT,
                                               int K, int N) {
  __shared__ unsigned short tile[32][33];
  const int n0 = blockIdx.x * 32, k0 = blockIdx.y * 32;
  const int tx = threadIdx.x & 31, ty = threadIdx.x >> 5;  // ty 0..7
#pragma unroll
  for (int i = 0; i < 4; i++) {
    int k = ty + i * 8;
    tile[k][tx] = f2bf(W[(long)(k0 + k) * N + n0 + tx]);
  }
  __syncthreads();
#pragma unroll
  for (int i = 0; i < 4; i++) {
    int n = ty + i * 8;
    WT[(long)(n0 + n) * K + k0 + tx] = tile[tx][n];
  }
}

// ---- 128x128 bf16 GEMM, A[M][K], BT[N][K]; MODE 0 = qkv scatter, 1 = f32 out ----
template <int MODE>
__global__ __launch_bounds__(256) void k_gemm(
    const unsigned short* __restrict__ A,
    const unsigned short* __restrict__ BT,
    const float* __restrict__ bias,
    void* __restrict__ out0,
    unsigned short* __restrict__ outk,
    unsigned short* __restrict__ outv,
    int M, int N, int K) {
  __shared__ __align__(16) unsigned short lds_a[128 * 32];
  __shared__ __align__(16) unsigned short lds_b[128 * 32];
  const int t = threadIdx.x;
  const int w = t >> 6, l = t & 63;
  const int g = l >> 4, x = l & 15;
  const int wr = w >> 1, wc = w & 1;
  const long m0 = (long)blockIdx.x * 128, n0 = (long)blockIdx.y * 128;

  f32x4 acc[4][4];
#pragma unroll
  for (int i = 0; i < 4; i++)
#pragma unroll
    for (int j = 0; j < 4; j++) acc[i][j] = (f32x4){0.f, 0.f, 0.f, 0.f};

  const unsigned short* ga = A + (m0 + 16 * w + (l >> 2)) * (long)K + (l & 3) * 8;
  const unsigned short* gb = BT + (n0 + 16 * w + (l >> 2)) * (long)K + (l & 3) * 8;
  unsigned short* la = lds_a + w * 512;
  unsigned short* lb = lds_b + w * 512;

  for (int k0 = 0; k0 < K; k0 += 32) {
    __syncthreads();
    gll16(ga + k0, la);
    gll16(ga + k0 + 64 * (long)K, la + 2048);
    gll16(gb + k0, lb);
    gll16(gb + k0 + 64 * (long)K, lb + 2048);
    __syncthreads();
    short8 af[4], bfr[4];
#pragma unroll
    for (int i = 0; i < 4; i++)
      af[i] = *reinterpret_cast<const short8*>(lds_a + (wr * 64 + i * 16 + x) * 32 + g * 8);
#pragma unroll
    for (int j = 0; j < 4; j++)
      bfr[j] = *reinterpret_cast<const short8*>(lds_b + (wc * 64 + j * 16 + x) * 32 + g * 8);
#pragma unroll
    for (int i = 0; i < 4; i++)
#pragma unroll
      for (int j = 0; j < 4; j++)
        acc[i][j] = __builtin_amdgcn_mfma_f32_16x16x32_bf16(af[i], bfr[j], acc[i][j], 0, 0, 0);
  }

#pragma unroll
  for (int i = 0; i < 4; i++) {
#pragma unroll
    for (int j = 0; j < 4; j++) {
#pragma unroll
      for (int r = 0; r < 4; r++) {
        const long m = m0 + wr * 64 + i * 16 + 4 * g + r;
        const long n = n0 + wc * 64 + j * 16 + x;
        float v = acc[i][j][r] + bias[n];
        if (MODE == 1) {
          ((float*)out0)[m * N + n] = v;
        } else {
          const int b = (int)(m >> 11), s = (int)(m & 2047);
          const int which = (int)(n >> 10);
          const int rem = (int)(n & 1023);
          const int h = rem >> 6, d = rem & 63;
          const long idx = (((long)(b * H_ + h)) * S_ + s) * DH_ + d;
          unsigned short bv = f2bf(v);
          if (which == 0) ((unsigned short*)out0)[idx] = bv;
          else if (which == 1) outk[idx] = bv;
          else outv[idx] = bv;
        }
      }
    }
  }
}

// ---- V [bh][s][dh] -> VT [bh][dh][s] ----
__global__ __launch_bounds__(256) void k_tr_v(const unsigned short* __restrict__ v,
                                              unsigned short* __restrict__ vt) {
  __shared__ __align__(16) unsigned short tile[64][72];
  const int bh = blockIdx.y;
  const int s0 = blockIdx.x * 64;
  const int t = threadIdx.x;
  const int r = t >> 2;
  const int c = (t & 3) * 16;
  const unsigned short* src = v + ((long)bh * S_ + s0 + r) * DH_ + c;
  *reinterpret_cast<short8*>(&tile[r][c]) = *reinterpret_cast<const short8*>(src);
  *reinterpret_cast<short8*>(&tile[r][c + 8]) = *reinterpret_cast<const short8*>(src + 8);
  __syncthreads();
  unsigned short* dst = vt + ((long)bh * DH_ + r) * S_ + s0 + c;
#pragma unroll
  for (int jj = 0; jj < 2; jj++) {
    short8 o;
#pragma unroll
    for (int j = 0; j < 8; j++) o[j] = (short)tile[c + jj * 8 + j][r];
    *reinterpret_cast<short8*>(dst + jj * 8) = o;
  }
}

// ---- causal flash attention: Q,K [bh][s][dh], VT [bh][dh][s] -> attn_out [b*s][H*DH] ----
__global__ __launch_bounds__(256) void k_attn(const unsigned short* __restrict__ qb,
                                              const unsigned short* __restrict__ kb,
                                              const unsigned short* __restrict__ vt,
                                              unsigned short* __restrict__ attn_out) {
  __shared__ __align__(16) unsigned short lds_k[64 * 64];
  __shared__ __align__(16) unsigned short lds_v[64 * 64];
  __shared__ __align__(16) unsigned short lds_p[4 * 16 * 72];

  const int t = threadIdx.x;
  const int w = t >> 6, l = t & 63;
  const int g = l >> 4, x = l & 15;
  const int bh = blockIdx.y;
  const int b = bh >> 4, h = bh & 15;
  const int q0 = blockIdx.x * 64;

  const long kvbase = (long)bh * S_ * DH_;

  short8 qf[2];
  {
    const unsigned short* qp = qb + kvbase + (long)(q0 + w * 16 + x) * DH_ + g * 8;
    qf[0] = *reinterpret_cast<const short8*>(qp);
    qf[1] = *reinterpret_cast<const short8*>(qp + 32);
  }

  f32x4 oacc[4];
#pragma unroll
  for (int dt = 0; dt < 4; dt++) oacc[dt] = (f32x4){0.f, 0.f, 0.f, 0.f};
  float mrow[4], lrow[4];
#pragma unroll
  for (int r = 0; r < 4; r++) { mrow[r] = -3.0e38f; lrow[r] = 0.f; }

  const int kv_end = q0 + 64;
  for (int kv0 = 0; kv0 < kv_end; kv0 += 64) {
    __syncthreads();
    {
      const unsigned short* ks = kb + kvbase + (long)(kv0 + 8 * w + (l >> 3)) * DH_ + (l & 7) * 8;
      gll16(ks, lds_k + w * 512);
      gll16(ks + 32 * DH_, lds_k + w * 512 + 2048);
      const unsigned short* vs = vt + ((long)bh * DH_ + 8 * w + (l >> 3)) * S_ + kv0 + (l & 7) * 8;
      gll16(vs, lds_v + w * 512);
      gll16(vs + 32 * (long)S_, lds_v + w * 512 + 2048);
    }
    __syncthreads();

    f32x4 sacc[4];
#pragma unroll
    for (int n = 0; n < 4; n++) {
      sacc[n] = (f32x4){0.f, 0.f, 0.f, 0.f};
#pragma unroll
      for (int c = 0; c < 2; c++) {
        short8 kf = *reinterpret_cast<const short8*>(lds_k + (n * 16 + x) * 64 + c * 32 + g * 8);
        sacc[n] = __builtin_amdgcn_mfma_f32_16x16x32_bf16(qf[c], kf, sacc[n], 0, 0, 0);
      }
    }

    float mloc[4] = {-3.0e38f, -3.0e38f, -3.0e38f, -3.0e38f};
    const int qgb = q0 + w * 16 + 4 * g;
#pragma unroll
    for (int n = 0; n < 4; n++) {
      const int kvg = kv0 + n * 16 + x;
#pragma unroll
      for (int r = 0; r < 4; r++) {
        float s = sacc[n][r] * 0.125f;
        if (kvg > qgb + r) s = -1.0e9f;
        sacc[n][r] = s;
        mloc[r] = fmaxf(mloc[r], s);
      }
    }
#pragma unroll
    for (int off = 1; off <= 8; off <<= 1)
#pragma unroll
      for (int r = 0; r < 4; r++)
        mloc[r] = fmaxf(mloc[r], __shfl_xor(mloc[r], off, 64));

    float fsc[4], psum[4];
#pragma unroll
    for (int r = 0; r < 4; r++) {
      float mnew = fmaxf(mrow[r], mloc[r]);
      fsc[r] = exp2f((mrow[r] - mnew) * LOG2E);
      mrow[r] = mnew;
      psum[r] = 0.f;
    }
    unsigned short* pl = lds_p + w * 1152;
#pragma unroll
    for (int n = 0; n < 4; n++) {
#pragma unroll
      for (int r = 0; r < 4; r++) {
        float p = exp2f((sacc[n][r] - mrow[r]) * LOG2E);
        psum[r] += p;
        pl[(4 * g + r) * 72 + n * 16 + x] = f2bf(p);
      }
    }
#pragma unroll
    for (int off = 1; off <= 8; off <<= 1)
#pragma unroll
      for (int r = 0; r < 4; r++)
        psum[r] += __shfl_xor(psum[r], off, 64);
#pragma unroll
    for (int r = 0; r < 4; r++) lrow[r] = lrow[r] * fsc[r] + psum[r];
#pragma unroll
    for (int dt = 0; dt < 4; dt++)
#pragma unroll
      for (int r = 0; r < 4; r++) oacc[dt][r] *= fsc[r];

#pragma unroll
    for (int c2 = 0; c2 < 2; c2++) {
      short8 pa = *reinterpret_cast<const short8*>(pl + x * 72 + c2 * 32 + g * 8);
#pragma unroll
      for (int dt = 0; dt < 4; dt++) {
        short8 vf = *reinterpret_cast<const short8*>(lds_v + (dt * 16 + x) * 64 + c2 * 32 + g * 8);
        oacc[dt] = __builtin_amdgcn_mfma_f32_16x16x32_bf16(pa, vf, oacc[dt], 0, 0, 0);
      }
    }
  }

#pragma unroll
  for (int dt = 0; dt < 4; dt++) {
#pragma unroll
    for (int r = 0; r < 4; r++) {
      float o = oacc[dt][r] / lrow[r];
      const long row = (long)b * S_ + q0 + w * 16 + 4 * g + r;
      attn_out[row * (H_ * DH_) + h * DH_ + dt * 16 + x] = f2bf(o);
    }
  }
}

extern "C" void kernel_launch(void* const* d_in, const int* in_sizes, int n_in,
                              void* d_out, int out_size, void* d_ws, size_t ws_size,
                              hipStream_t stream) {
  (void)in_sizes; (void)n_in; (void)out_size; (void)ws_size;
  const float* hs    = (const float*)d_in[0];
  // d_in[1] = attention_mask: deterministic causal tril, applied analytically.
  const float* Wqkv  = (const float*)d_in[2];
  const float* bqkv  = (const float*)d_in[3];
  const float* Wproj = (const float*)d_in[4];
  const float* bproj = (const float*)d_in[5];
  float* out = (float*)d_out;

  unsigned short* ws    = (unsigned short*)d_ws;
  unsigned short* hid   = ws;                 // 4096*1024
  unsigned short* wqkvT = hid + 4194304;      // 3072*1024
  unsigned short* wprT  = wqkvT + 3145728;    // 1024*1024
  unsigned short* q_b   = wprT + 1048576;     // [bh][s][dh]
  unsigned short* k_b   = q_b + 4194304;
  unsigned short* v_b   = k_b + 4194304;
  unsigned short* vt_b  = v_b + 4194304;      // [bh][dh][s]
  unsigned short* ao    = vt_b + 4194304;     // [b*s][H*DH]

  k_cvt<<<4096, 256, 0, stream>>>(hs, hid, 1048576);
  k_cvt_t<<<dim3(96, 32), 256, 0, stream>>>(Wqkv, wqkvT, 1024, 3072);
  k_cvt_t<<<dim3(32, 32), 256, 0, stream>>>(Wproj, wprT, 1024, 1024);
  k_gemm<0><<<dim3(32, 24), 256, 0, stream>>>(hid, wqkvT, bqkv, (void*)q_b, k_b, v_b,
                                              4096, 3072, 1024);
  k_tr_v<<<dim3(32, 32), 256, 0, stream>>>(v_b, vt_b);
  k_attn<<<dim3(32, 32), 256, 0, stream>>>(q_b, k_b, vt_b, ao);
  k_gemm<1><<<dim3(32, 8), 256, 0, stream>>>(ao, wprT, bproj, (void*)out, nullptr, nullptr,
                                             4096, 1024, 1024);
}

// Round 2
// 245.348 us; speedup vs baseline: 1.2580x; 1.2580x over previous
//
#include <hip/hip_runtime.h>
#include <stdint.h>

#define B_ 2
#define S_ 2048
#define D_ 1024
#define H_ 16
#define DH_ 64
#define M_ 4096
#define LOG2E 1.44269504088896340736f

typedef __attribute__((ext_vector_type(8))) short short8;
typedef __attribute__((ext_vector_type(4))) float f32x4;

__device__ __forceinline__ unsigned short f2bf(float f) {
  union { float f; uint32_t u; } x; x.f = f;
  uint32_t u = x.u;
  u += 0x7FFFu + ((u >> 16) & 1u);
  return (unsigned short)(u >> 16);
}

__device__ __forceinline__ void gll16(const void* g, void* l) {
  __builtin_amdgcn_global_load_lds(
      (__attribute__((address_space(1))) void*)(g),
      (__attribute__((address_space(3))) void*)(l), 16, 0, 0);
}

// ---- f32 -> bf16 flat convert (4 elems/thread) ----
__global__ __launch_bounds__(256) void k_cvt(const float* __restrict__ in,
                                             unsigned short* __restrict__ out, int n4) {
  int i = blockIdx.x * 256 + threadIdx.x;
  if (i < n4) {
    float4 v = reinterpret_cast<const float4*>(in)[i];
    ushort4 o;
    o.x = f2bf(v.x); o.y = f2bf(v.y); o.z = f2bf(v.z); o.w = f2bf(v.w);
    reinterpret_cast<ushort4*>(out)[i] = o;
  }
}

// ---- W [K][N] f32 -> WT [N][K] bf16 (32x32 LDS tile) ----
__global__ __launch_bounds__(256) void k_cvt_t(const float* __restrict__ W,
                                               unsigned short* __restrict__ WT,
                                               int K, int N) {
  __shared__ unsigned short tile[32][33];
  const int n0 = blockIdx.x * 32, k0 = blockIdx.y * 32;
  const int tx = threadIdx.x & 31, ty = threadIdx.x >> 5;  // ty 0..7
#pragma unroll
  for (int i = 0; i < 4; i++) {
    int k = ty + i * 8;
    tile[k][tx] = f2bf(W[(long)(k0 + k) * N + n0 + tx]);
  }
  __syncthreads();
#pragma unroll
  for (int i = 0; i < 4; i++) {
    int n = ty + i * 8;
    WT[(long)(n0 + n) * K + k0 + tx] = tile[tx][n];
  }
}

// ---- 128x128 bf16 GEMM, A[M][K], BT[N][K]; MODE 0 = qkv scatter, 1 = f32 out ----
template <int MODE>
__global__ __launch_bounds__(256) void k_gemm(
    const unsigned short* __restrict__ A,
    const unsigned short* __restrict__ BT,
    const float* __restrict__ bias,
    void* __restrict__ out0,
    unsigned short* __restrict__ outk,
    unsigned short* __restrict__ outv,
    int M, int N, int K) {
  __shared__ __align__(16) unsigned short lds_a[128 * 32];
  __shared__ __align__(16) unsigned short lds_b[128 * 32];
  const int t = threadIdx.x;
  const int w = t >> 6, l = t & 63;
  const int g = l >> 4, x = l & 15;
  const int wr = w >> 1, wc = w & 1;
  const long m0 = (long)blockIdx.x * 128, n0 = (long)blockIdx.y * 128;

  f32x4 acc[4][4];
#pragma unroll
  for (int i = 0; i < 4; i++)
#pragma unroll
    for (int j = 0; j < 4; j++) acc[i][j] = (f32x4){0.f, 0.f, 0.f, 0.f};

  const unsigned short* ga = A + (m0 + 16 * w + (l >> 2)) * (long)K + (l & 3) * 8;
  const unsigned short* gb = BT + (n0 + 16 * w + (l >> 2)) * (long)K + (l & 3) * 8;
  unsigned short* la = lds_a + w * 512;
  unsigned short* lb = lds_b + w * 512;

  for (int k0 = 0; k0 < K; k0 += 32) {
    __syncthreads();
    gll16(ga + k0, la);
    gll16(ga + k0 + 64 * (long)K, la + 2048);
    gll16(gb + k0, lb);
    gll16(gb + k0 + 64 * (long)K, lb + 2048);
    __syncthreads();
    short8 af[4], bfr[4];
#pragma unroll
    for (int i = 0; i < 4; i++)
      af[i] = *reinterpret_cast<const short8*>(lds_a + (wr * 64 + i * 16 + x) * 32 + g * 8);
#pragma unroll
    for (int j = 0; j < 4; j++)
      bfr[j] = *reinterpret_cast<const short8*>(lds_b + (wc * 64 + j * 16 + x) * 32 + g * 8);
#pragma unroll
    for (int i = 0; i < 4; i++)
#pragma unroll
      for (int j = 0; j < 4; j++)
        acc[i][j] = __builtin_amdgcn_mfma_f32_16x16x32_bf16(af[i], bfr[j], acc[i][j], 0, 0, 0);
  }

#pragma unroll
  for (int i = 0; i < 4; i++) {
#pragma unroll
    for (int j = 0; j < 4; j++) {
#pragma unroll
      for (int r = 0; r < 4; r++) {
        const long m = m0 + wr * 64 + i * 16 + 4 * g + r;
        const long n = n0 + wc * 64 + j * 16 + x;
        float v = acc[i][j][r] + bias[n];
        if (MODE == 1) {
          ((float*)out0)[m * N + n] = v;
        } else {
          const int b = (int)(m >> 11), s = (int)(m & 2047);
          const int which = (int)(n >> 10);
          const int rem = (int)(n & 1023);
          const int h = rem >> 6, d = rem & 63;
          const long idx = (((long)(b * H_ + h)) * S_ + s) * DH_ + d;
          unsigned short bv = f2bf(v);
          if (which == 0) ((unsigned short*)out0)[idx] = bv;
          else if (which == 1) outk[idx] = bv;
          else outv[idx] = bv;
        }
      }
    }
  }
}

// ---- V [bh][s][dh] -> VT [bh][dh][s] ----
__global__ __launch_bounds__(256) void k_tr_v(const unsigned short* __restrict__ v,
                                              unsigned short* __restrict__ vt) {
  __shared__ __align__(16) unsigned short tile[64][72];
  const int bh = blockIdx.y;
  const int s0 = blockIdx.x * 64;
  const int t = threadIdx.x;
  const int r = t >> 2;
  const int c = (t & 3) * 16;
  const unsigned short* src = v + ((long)bh * S_ + s0 + r) * DH_ + c;
  *reinterpret_cast<short8*>(&tile[r][c]) = *reinterpret_cast<const short8*>(src);
  *reinterpret_cast<short8*>(&tile[r][c + 8]) = *reinterpret_cast<const short8*>(src + 8);
  __syncthreads();
  unsigned short* dst = vt + ((long)bh * DH_ + r) * S_ + s0 + c;
#pragma unroll
  for (int jj = 0; jj < 2; jj++) {
    short8 o;
#pragma unroll
    for (int j = 0; j < 8; j++) o[j] = (short)tile[c + jj * 8 + j][r];
    *reinterpret_cast<short8*>(dst + jj * 8) = o;
  }
}

// ---- causal flash attention, paired q-tiles (qb, 31-qb), XOR-swizzled LDS ----
// K/V/P tiles stored with physical_chunk16B = logical_chunk ^ (row&7).
// global_load_lds writes linearly, so the SOURCE address is pre-swizzled
// (staging lane l covers row-within-8 = l>>3, chunk = l&7 -> load chunk (l&7)^(l>>3)).
__global__ __launch_bounds__(256) void k_attn(const unsigned short* __restrict__ qb_,
                                              const unsigned short* __restrict__ kb,
                                              const unsigned short* __restrict__ vt,
                                              unsigned short* __restrict__ attn_out) {
  __shared__ __align__(16) unsigned short lds_k[64 * 64];
  __shared__ __align__(16) unsigned short lds_v[64 * 64];
  __shared__ __align__(16) unsigned short lds_p[4 * 16 * 64];

  const int t = threadIdx.x;
  const int w = t >> 6, l = t & 63;
  const int g = l >> 4, x = l & 15;
  const int lr = l >> 3, lc = l & 7;     // staging row/chunk within wave's 8-row slab
  const int sch = lc ^ lr;               // pre-swizzled source chunk
  const int bh = blockIdx.y;
  const int b = bh >> 4, h = bh & 15;

  const long kvbase = (long)bh * S_ * DH_;
  unsigned short* pl = lds_p + w * 1024;

#pragma unroll 1
  for (int pass = 0; pass < 2; pass++) {
    const int qtile = pass ? blockIdx.x : (31 - blockIdx.x);
    const int q0 = qtile * 64;

    short8 qf[2];
    {
      const unsigned short* qp = qb_ + kvbase + (long)(q0 + w * 16 + x) * DH_ + g * 8;
      qf[0] = *reinterpret_cast<const short8*>(qp);
      qf[1] = *reinterpret_cast<const short8*>(qp + 32);
    }

    f32x4 oacc[4];
#pragma unroll
    for (int dt = 0; dt < 4; dt++) oacc[dt] = (f32x4){0.f, 0.f, 0.f, 0.f};
    float mrow[4], lrow[4];
#pragma unroll
    for (int r = 0; r < 4; r++) { mrow[r] = -3.0e38f; lrow[r] = 0.f; }

    const int kv_end = q0 + 64;
    for (int kv0 = 0; kv0 < kv_end; kv0 += 64) {
      __syncthreads();
      {
        const unsigned short* ks = kb + kvbase + (long)(kv0 + 8 * w + lr) * DH_ + sch * 8;
        gll16(ks, lds_k + w * 512);
        gll16(ks + 32 * DH_, lds_k + w * 512 + 2048);
        const unsigned short* vs = vt + ((long)bh * DH_ + 8 * w + lr) * S_ + kv0 + sch * 8;
        gll16(vs, lds_v + w * 512);
        gll16(vs + 32 * (long)S_, lds_v + w * 512 + 2048);
      }
      __syncthreads();

      f32x4 sacc[4];
#pragma unroll
      for (int n = 0; n < 4; n++) {
        sacc[n] = (f32x4){0.f, 0.f, 0.f, 0.f};
#pragma unroll
        for (int c = 0; c < 2; c++) {
          short8 kf = *reinterpret_cast<const short8*>(
              lds_k + (n * 16 + x) * 64 + (((4 * c + g) ^ (x & 7)) << 3));
          sacc[n] = __builtin_amdgcn_mfma_f32_16x16x32_bf16(qf[c], kf, sacc[n], 0, 0, 0);
        }
      }

      float mloc[4] = {-3.0e38f, -3.0e38f, -3.0e38f, -3.0e38f};
      const int qgb = q0 + w * 16 + 4 * g;
#pragma unroll
      for (int n = 0; n < 4; n++) {
        const int kvg = kv0 + n * 16 + x;
#pragma unroll
        for (int r = 0; r < 4; r++) {
          float s = sacc[n][r] * 0.125f;
          if (kvg > qgb + r) s = -1.0e9f;
          sacc[n][r] = s;
          mloc[r] = fmaxf(mloc[r], s);
        }
      }
#pragma unroll
      for (int off = 1; off <= 8; off <<= 1)
#pragma unroll
        for (int r = 0; r < 4; r++)
          mloc[r] = fmaxf(mloc[r], __shfl_xor(mloc[r], off, 64));

      float fsc[4], psum[4];
#pragma unroll
      for (int r = 0; r < 4; r++) {
        float mnew = fmaxf(mrow[r], mloc[r]);
        fsc[r] = exp2f((mrow[r] - mnew) * LOG2E);
        mrow[r] = mnew;
        psum[r] = 0.f;
      }
#pragma unroll
      for (int n = 0; n < 4; n++) {
#pragma unroll
        for (int r = 0; r < 4; r++) {
          float p = exp2f((sacc[n][r] - mrow[r]) * LOG2E);
          psum[r] += p;
          const int row = 4 * g + r;
          pl[row * 64 + (((2 * n + (x >> 3)) ^ (row & 7)) << 3) + (x & 7)] = f2bf(p);
        }
      }
#pragma unroll
      for (int off = 1; off <= 8; off <<= 1)
#pragma unroll
        for (int r = 0; r < 4; r++)
          psum[r] += __shfl_xor(psum[r], off, 64);
#pragma unroll
      for (int r = 0; r < 4; r++) lrow[r] = lrow[r] * fsc[r] + psum[r];
#pragma unroll
      for (int dt = 0; dt < 4; dt++)
#pragma unroll
        for (int r = 0; r < 4; r++) oacc[dt][r] *= fsc[r];

#pragma unroll
      for (int c2 = 0; c2 < 2; c2++) {
        short8 pa = *reinterpret_cast<const short8*>(
            pl + x * 64 + (((4 * c2 + g) ^ (x & 7)) << 3));
#pragma unroll
        for (int dt = 0; dt < 4; dt++) {
          short8 vf = *reinterpret_cast<const short8*>(
              lds_v + (dt * 16 + x) * 64 + (((4 * c2 + g) ^ (x & 7)) << 3));
          oacc[dt] = __builtin_amdgcn_mfma_f32_16x16x32_bf16(pa, vf, oacc[dt], 0, 0, 0);
        }
      }
    }

#pragma unroll
    for (int dt = 0; dt < 4; dt++) {
#pragma unroll
      for (int r = 0; r < 4; r++) {
        float o = oacc[dt][r] / lrow[r];
        const long row = (long)b * S_ + q0 + w * 16 + 4 * g + r;
        attn_out[row * (H_ * DH_) + h * DH_ + dt * 16 + x] = f2bf(o);
      }
    }
  }
}

extern "C" void kernel_launch(void* const* d_in, const int* in_sizes, int n_in,
                              void* d_out, int out_size, void* d_ws, size_t ws_size,
                              hipStream_t stream) {
  (void)in_sizes; (void)n_in; (void)out_size; (void)ws_size;
  const float* hs    = (const float*)d_in[0];
  // d_in[1] = attention_mask: deterministic causal tril, applied analytically.
  const float* Wqkv  = (const float*)d_in[2];
  const float* bqkv  = (const float*)d_in[3];
  const float* Wproj = (const float*)d_in[4];
  const float* bproj = (const float*)d_in[5];
  float* out = (float*)d_out;

  unsigned short* ws    = (unsigned short*)d_ws;
  unsigned short* hid   = ws;                 // 4096*1024
  unsigned short* wqkvT = hid + 4194304;      // 3072*1024
  unsigned short* wprT  = wqkvT + 3145728;    // 1024*1024
  unsigned short* q_b   = wprT + 1048576;     // [bh][s][dh]
  unsigned short* k_b   = q_b + 4194304;
  unsigned short* v_b   = k_b + 4194304;
  unsigned short* vt_b  = v_b + 4194304;      // [bh][dh][s]
  unsigned short* ao    = vt_b + 4194304;     // [b*s][H*DH]

  k_cvt<<<4096, 256, 0, stream>>>(hs, hid, 1048576);
  k_cvt_t<<<dim3(96, 32), 256, 0, stream>>>(Wqkv, wqkvT, 1024, 3072);
  k_cvt_t<<<dim3(32, 32), 256, 0, stream>>>(Wproj, wprT, 1024, 1024);
  k_gemm<0><<<dim3(32, 24), 256, 0, stream>>>(hid, wqkvT, bqkv, (void*)q_b, k_b, v_b,
                                              4096, 3072, 1024);
  k_tr_v<<<dim3(32, 32), 256, 0, stream>>>(v_b, vt_b);
  k_attn<<<dim3(16, 32), 256, 0, stream>>>(q_b, k_b, vt_b, ao);
  k_gemm<1><<<dim3(32, 8), 256, 0, stream>>>(ao, wprT, bproj, (void*)out, nullptr, nullptr,
                                             4096, 1024, 1024);
}

// Round 4
// 239.354 us; speedup vs baseline: 1.2895x; 1.0250x over previous
//
#include <hip/hip_runtime.h>
#include <stdint.h>

#define B_ 2
#define S_ 2048
#define D_ 1024
#define H_ 16
#define DH_ 64
#define M_ 4096
#define LOG2E 1.44269504088896340736f

typedef __attribute__((ext_vector_type(8))) short short8;
typedef __attribute__((ext_vector_type(4))) float f32x4;
typedef __attribute__((ext_vector_type(16))) float f32x16;

__device__ __forceinline__ unsigned short f2bf(float f) {
  union { float f; uint32_t u; } x; x.f = f;
  uint32_t u = x.u;
  u += 0x7FFFu + ((u >> 16) & 1u);
  return (unsigned short)(u >> 16);
}

__device__ __forceinline__ unsigned int pack_bf(float lo, float hi2) {
  return (unsigned int)f2bf(lo) | ((unsigned int)f2bf(hi2) << 16);
}

__device__ __forceinline__ void gll16(const void* g, void* l) {
  __builtin_amdgcn_global_load_lds(
      (__attribute__((address_space(1))) void*)(g),
      (__attribute__((address_space(3))) void*)(l), 16, 0, 0);
}

// ---- f32 -> bf16 flat convert (4 elems/thread) ----
__global__ __launch_bounds__(256) void k_cvt(const float* __restrict__ in,
                                             unsigned short* __restrict__ out, int n4) {
  int i = blockIdx.x * 256 + threadIdx.x;
  if (i < n4) {
    float4 v = reinterpret_cast<const float4*>(in)[i];
    ushort4 o;
    o.x = f2bf(v.x); o.y = f2bf(v.y); o.z = f2bf(v.z); o.w = f2bf(v.w);
    reinterpret_cast<ushort4*>(out)[i] = o;
  }
}

// ---- W [K][N] f32 -> WT [N][K] bf16 (32x32 LDS tile) ----
__global__ __launch_bounds__(256) void k_cvt_t(const float* __restrict__ W,
                                               unsigned short* __restrict__ WT,
                                               int K, int N) {
  __shared__ unsigned short tile[32][33];
  const int n0 = blockIdx.x * 32, k0 = blockIdx.y * 32;
  const int tx = threadIdx.x & 31, ty = threadIdx.x >> 5;  // ty 0..7
#pragma unroll
  for (int i = 0; i < 4; i++) {
    int k = ty + i * 8;
    tile[k][tx] = f2bf(W[(long)(k0 + k) * N + n0 + tx]);
  }
  __syncthreads();
#pragma unroll
  for (int i = 0; i < 4; i++) {
    int n = ty + i * 8;
    WT[(long)(n0 + n) * K + k0 + tx] = tile[tx][n];
  }
}

// ---- 128x128 bf16 GEMM, A[M][K], BT[N][K]; MODE 0 = qkv scatter, 1 = f32 out ----
template <int MODE>
__global__ __launch_bounds__(256) void k_gemm(
    const unsigned short* __restrict__ A,
    const unsigned short* __restrict__ BT,
    const float* __restrict__ bias,
    void* __restrict__ out0,
    unsigned short* __restrict__ outk,
    unsigned short* __restrict__ outv,
    int M, int N, int K) {
  __shared__ __align__(16) unsigned short lds_a[128 * 32];
  __shared__ __align__(16) unsigned short lds_b[128 * 32];
  const int t = threadIdx.x;
  const int w = t >> 6, l = t & 63;
  const int g = l >> 4, x = l & 15;
  const int wr = w >> 1, wc = w & 1;
  const long m0 = (long)blockIdx.x * 128, n0 = (long)blockIdx.y * 128;

  f32x4 acc[4][4];
#pragma unroll
  for (int i = 0; i < 4; i++)
#pragma unroll
    for (int j = 0; j < 4; j++) acc[i][j] = (f32x4){0.f, 0.f, 0.f, 0.f};

  const unsigned short* ga = A + (m0 + 16 * w + (l >> 2)) * (long)K + (l & 3) * 8;
  const unsigned short* gb = BT + (n0 + 16 * w + (l >> 2)) * (long)K + (l & 3) * 8;
  unsigned short* la = lds_a + w * 512;
  unsigned short* lb = lds_b + w * 512;

  for (int k0 = 0; k0 < K; k0 += 32) {
    __syncthreads();
    gll16(ga + k0, la);
    gll16(ga + k0 + 64 * (long)K, la + 2048);
    gll16(gb + k0, lb);
    gll16(gb + k0 + 64 * (long)K, lb + 2048);
    __syncthreads();
    short8 af[4], bfr[4];
#pragma unroll
    for (int i = 0; i < 4; i++)
      af[i] = *reinterpret_cast<const short8*>(lds_a + (wr * 64 + i * 16 + x) * 32 + g * 8);
#pragma unroll
    for (int j = 0; j < 4; j++)
      bfr[j] = *reinterpret_cast<const short8*>(lds_b + (wc * 64 + j * 16 + x) * 32 + g * 8);
#pragma unroll
    for (int i = 0; i < 4; i++)
#pragma unroll
      for (int j = 0; j < 4; j++)
        acc[i][j] = __builtin_amdgcn_mfma_f32_16x16x32_bf16(af[i], bfr[j], acc[i][j], 0, 0, 0);
  }

#pragma unroll
  for (int i = 0; i < 4; i++) {
#pragma unroll
    for (int j = 0; j < 4; j++) {
#pragma unroll
      for (int r = 0; r < 4; r++) {
        const long m = m0 + wr * 64 + i * 16 + 4 * g + r;
        const long n = n0 + wc * 64 + j * 16 + x;
        float v = acc[i][j][r] + bias[n];
        if (MODE == 1) {
          ((float*)out0)[m * N + n] = v;
        } else {
          const int b = (int)(m >> 11), s = (int)(m & 2047);
          const int which = (int)(n >> 10);
          const int rem = (int)(n & 1023);
          const int h = rem >> 6, d = rem & 63;
          const long idx = (((long)(b * H_ + h)) * S_ + s) * DH_ + d;
          unsigned short bv = f2bf(v);
          if (which == 0) ((unsigned short*)out0)[idx] = bv;
          else if (which == 1) outk[idx] = bv;
          else outv[idx] = bv;
        }
      }
    }
  }
}

// ---- V [bh][s][dh] -> VT [bh][dh][s] ----
__global__ __launch_bounds__(256) void k_tr_v(const unsigned short* __restrict__ v,
                                              unsigned short* __restrict__ vt) {
  __shared__ __align__(16) unsigned short tile[64][72];
  const int bh = blockIdx.y;
  const int s0 = blockIdx.x * 64;
  const int t = threadIdx.x;
  const int r = t >> 2;
  const int c = (t & 3) * 16;
  const unsigned short* src = v + ((long)bh * S_ + s0 + r) * DH_ + c;
  *reinterpret_cast<short8*>(&tile[r][c]) = *reinterpret_cast<const short8*>(src);
  *reinterpret_cast<short8*>(&tile[r][c + 8]) = *reinterpret_cast<const short8*>(src + 8);
  __syncthreads();
  unsigned short* dst = vt + ((long)bh * DH_ + r) * S_ + s0 + c;
#pragma unroll
  for (int jj = 0; jj < 2; jj++) {
    short8 o;
#pragma unroll
    for (int j = 0; j < 8; j++) o[j] = (short)tile[c + jj * 8 + j][r];
    *reinterpret_cast<short8*>(dst + jj * 8) = o;
  }
}

// ---- causal flash attention, 32x32 MFMA, swapped QK^T, in-register softmax ----
// Known-good cross-lane primitives only (__shfl_xor, ds_bpermute); PA words built
// by explicit bf16 bit-packing + lane^32 shuffle + per-word select, derived from
// the HW-verified 32x32 D layout: row=(r&3)+8*(r>>2)+4*hi, col=lane&31.
__global__ __launch_bounds__(256, 1) void k_attn(const unsigned short* __restrict__ qb_,
                                                 const unsigned short* __restrict__ kb,
                                                 const unsigned short* __restrict__ vt,
                                                 unsigned short* __restrict__ attn_out) {
  __shared__ __align__(16) unsigned short lds_k[2][4096];
  __shared__ __align__(16) unsigned short lds_v[2][4096];

  const int t0 = threadIdx.x;
  const int w = t0 >> 6, l = t0 & 63;
  const int q32 = l & 31, hi = l >> 5;
  const int r7 = q32 & 7;
  const int lr = l >> 3, sch = (l & 7) ^ lr;  // staging: pre-swizzled source chunk
  const int bh = blockIdx.y;
  const int b = bh >> 4, h = bh & 15;
  const long kvbase = (long)bh * S_ * DH_;
  const long vtbase = (long)bh * DH_ * S_;
  const float SC = 0.125f * LOG2E;  // scores kept in log2 domain

#pragma unroll 1
  for (int pass = 0; pass < 2; pass++) {
    const int qc = pass ? (15 - blockIdx.x) : blockIdx.x;
    const int q0p = qc * 128;
    const int q0w = q0p + 32 * w;
    const int qg = q0w + q32;
    const int nt = 2 * qc + 2;

    // Q fragments (B-operand): row qg, dh = 16f + 8*hi + j
    short8 qf[4];
#pragma unroll
    for (int f = 0; f < 4; f++)
      qf[f] = *reinterpret_cast<const short8*>(qb_ + kvbase + (long)qg * DH_ + 16 * f + 8 * hi);

    // stage tile 0 into buf 0
#pragma unroll
    for (int i = 0; i < 2; i++) {
      gll16(kb + kvbase + (long)(16 * w + 8 * i + lr) * DH_ + sch * 8,
            &lds_k[0][w * 1024 + i * 512]);
      gll16(vt + vtbase + (long)(16 * w + 8 * i + lr) * S_ + sch * 8,
            &lds_v[0][w * 1024 + i * 512]);
    }

    f32x16 oacc[2];
#pragma unroll
    for (int dt = 0; dt < 2; dt++)
#pragma unroll
      for (int r = 0; r < 16; r++) oacc[dt][r] = 0.f;
    float m = -1.0e30f, lown = 0.f;

    asm volatile("s_waitcnt vmcnt(0)" ::: "memory");
    __syncthreads();

    for (int tt = 0; tt < nt; tt++) {
      const int kv0 = tt * 64;
      // prefetch next tile into other buffer
      if (tt + 1 < nt) {
        const int nb = (tt + 1) & 1;
        const int kvn = kv0 + 64;
#pragma unroll
        for (int i = 0; i < 2; i++) {
          gll16(kb + kvbase + (long)(kvn + 16 * w + 8 * i + lr) * DH_ + sch * 8,
                &lds_k[nb][w * 1024 + i * 512]);
          gll16(vt + vtbase + (long)(16 * w + 8 * i + lr) * S_ + kvn + sch * 8,
                &lds_v[nb][w * 1024 + i * 512]);
        }
      }

      if (kv0 <= q0w + 31) {  // warp has live rows in this tile
        const unsigned short* lk = lds_k[tt & 1];
        const unsigned short* lv = lds_v[tt & 1];

        // QK^T (swapped): sa[ks][reg] = S^T[kv = 32ks + R(reg,hi)][q = q32]
        f32x16 sa[2];
#pragma unroll
        for (int ks = 0; ks < 2; ks++) {
#pragma unroll
          for (int r = 0; r < 16; r++) sa[ks][r] = 0.f;
#pragma unroll
          for (int f = 0; f < 4; f++) {
            short8 kf = *reinterpret_cast<const short8*>(
                lk + (32 * ks + q32) * 64 + (((2 * f + hi) ^ r7) << 3));
            sa[ks] = __builtin_amdgcn_mfma_f32_32x32x16_bf16(kf, qf[f], sa[ks], 0, 0, 0);
          }
        }

        float p[32];
#pragma unroll
        for (int ks = 0; ks < 2; ks++)
#pragma unroll
          for (int r = 0; r < 16; r++) p[16 * ks + r] = sa[ks][r] * SC;

        const bool diag = (kv0 + 63 > q0w);
        if (diag) {
#pragma unroll
          for (int ks = 0; ks < 2; ks++)
#pragma unroll
            for (int r = 0; r < 16; r++) {
              const int kvg = kv0 + 32 * ks + (r & 3) + 8 * (r >> 2) + 4 * hi;
              if (kvg > qg) p[16 * ks + r] = -1.0e30f;
            }
        }

        // tile max (in-lane tree + lane^32 partner)
        float mx[16];
#pragma unroll
        for (int r = 0; r < 16; r++) mx[r] = fmaxf(p[r], p[r + 16]);
#pragma unroll
        for (int st = 8; st >= 1; st >>= 1)
#pragma unroll
          for (int r = 0; r < 8; r++)
            if (r < st) mx[r] = fmaxf(mx[r], mx[r + st]);
        float pmax = fmaxf(mx[0], __shfl_xor(mx[0], 32, 64));

        // defer-max rescale (THR = 8 in log2 domain)
        if (__any(pmax > m + 8.0f)) {
          const float mn = fmaxf(m, pmax);
          const float fsc = exp2f(m - mn);
          m = mn;
          lown *= fsc;
#pragma unroll
          for (int r = 0; r < 16; r++) {
            const int rr = (r & 3) + 8 * (r >> 2) + 4 * hi;
            const float fr = __int_as_float(
                __builtin_amdgcn_ds_bpermute(rr << 2, __float_as_int(fsc)));
            oacc[0][r] *= fr;
            oacc[1][r] *= fr;
          }
        }

        // exp (log2 domain)
#pragma unroll
        for (int i = 0; i < 32; i++) p[i] = exp2f(p[i] - m);

        // own-half row sum (partner combined once at pass end)
        float sm[16];
#pragma unroll
        for (int r = 0; r < 16; r++) sm[r] = p[r] + p[r + 16];
#pragma unroll
        for (int st = 8; st >= 1; st >>= 1)
#pragma unroll
          for (int r = 0; r < 8; r++)
            if (r < st) sm[r] += sm[r + st];
        lown += sm[0];

        // PV: 4 k-steps of 16 kv. A-word j-pair for this lane must hold
        // P[q32][kv = 16*s4 + 8*hi + {2j, 2j+1}]. Own p labels: kv = 16*s4
        // + 4*hi + {0..3} (t0,t1) and + 8 + 4*hi + {0..3} (t2,t3); the
        // other half's words come from the lane^32 partner.
#pragma unroll
        for (int s4 = 0; s4 < 4; s4++) {
          const int bse = 8 * s4;
          unsigned int t0 = pack_bf(p[bse + 0], p[bse + 1]);
          unsigned int t1 = pack_bf(p[bse + 2], p[bse + 3]);
          unsigned int t2 = pack_bf(p[bse + 4], p[bse + 5]);
          unsigned int t3 = pack_bf(p[bse + 6], p[bse + 7]);
          unsigned int t0x = __shfl_xor(t0, 32, 64);
          unsigned int t1x = __shfl_xor(t1, 32, 64);
          unsigned int t2x = __shfl_xor(t2, 32, 64);
          unsigned int t3x = __shfl_xor(t3, 32, 64);
          union { unsigned int u[4]; short8 s8; } pa;
          pa.u[0] = hi ? t2x : t0;  // kv +{0,1}  (hi=1: 8+{0,1} from partner)
          pa.u[1] = hi ? t3x : t1;  // kv +{2,3}
          pa.u[2] = hi ? t2 : t0x;  // kv +{4,5}  (hi=0: from partner; hi=1: own 12,13)
          pa.u[3] = hi ? t3 : t1x;  // kv +{6,7}
#pragma unroll
          for (int dt = 0; dt < 2; dt++) {
            short8 vf = *reinterpret_cast<const short8*>(
                lv + (32 * dt + q32) * 64 + (((2 * s4 + hi) ^ r7) << 3));
            oacc[dt] = __builtin_amdgcn_mfma_f32_32x32x16_bf16(pa.s8, vf, oacc[dt], 0, 0, 0);
          }
        }
      }

      asm volatile("s_waitcnt vmcnt(0)" ::: "memory");
      __syncthreads();
    }

    // epilogue: combine partner half, normalize, store
    const float lt = lown + __shfl_xor(lown, 32, 64);
    const float linv = 1.0f / lt;
#pragma unroll
    for (int r = 0; r < 16; r++) {
      const int rr = (r & 3) + 8 * (r >> 2) + 4 * hi;
      const float li = __int_as_float(
          __builtin_amdgcn_ds_bpermute(rr << 2, __float_as_int(linv)));
      const long row = (long)b * S_ + q0w + rr;
#pragma unroll
      for (int dt = 0; dt < 2; dt++)
        attn_out[row * (H_ * DH_) + h * DH_ + 32 * dt + q32] = f2bf(oacc[dt][r] * li);
    }
  }
}

extern "C" void kernel_launch(void* const* d_in, const int* in_sizes, int n_in,
                              void* d_out, int out_size, void* d_ws, size_t ws_size,
                              hipStream_t stream) {
  (void)in_sizes; (void)n_in; (void)out_size; (void)ws_size;
  const float* hs    = (const float*)d_in[0];
  // d_in[1] = attention_mask: deterministic causal tril, applied analytically.
  const float* Wqkv  = (const float*)d_in[2];
  const float* bqkv  = (const float*)d_in[3];
  const float* Wproj = (const float*)d_in[4];
  const float* bproj = (const float*)d_in[5];
  float* out = (float*)d_out;

  unsigned short* ws    = (unsigned short*)d_ws;
  unsigned short* hid   = ws;                 // 4096*1024
  unsigned short* wqkvT = hid + 4194304;      // 3072*1024
  unsigned short* wprT  = wqkvT + 3145728;    // 1024*1024
  unsigned short* q_b   = wprT + 1048576;     // [bh][s][dh]
  unsigned short* k_b   = q_b + 4194304;
  unsigned short* v_b   = k_b + 4194304;
  unsigned short* vt_b  = v_b + 4194304;      // [bh][dh][s]
  unsigned short* ao    = vt_b + 4194304;     // [b*s][H*DH]

  k_cvt<<<4096, 256, 0, stream>>>(hs, hid, 1048576);
  k_cvt_t<<<dim3(96, 32), 256, 0, stream>>>(Wqkv, wqkvT, 1024, 3072);
  k_cvt_t<<<dim3(32, 32), 256, 0, stream>>>(Wproj, wprT, 1024, 1024);
  k_gemm<0><<<dim3(32, 24), 256, 0, stream>>>(hid, wqkvT, bqkv, (void*)q_b, k_b, v_b,
                                              4096, 3072, 1024);
  k_tr_v<<<dim3(32, 32), 256, 0, stream>>>(v_b, vt_b);
  k_attn<<<dim3(8, 32), 256, 0, stream>>>(q_b, k_b, vt_b, ao);
  k_gemm<1><<<dim3(32, 8), 256, 0, stream>>>(ao, wprT, bproj, (void*)out, nullptr, nullptr,
                                             4096, 1024, 1024);
}

// Round 5
// 224.737 us; speedup vs baseline: 1.3734x; 1.0650x over previous
//
#include <hip/hip_runtime.h>
#include <stdint.h>

#define B_ 2
#define S_ 2048
#define D_ 1024
#define H_ 16
#define DH_ 64
#define M_ 4096
#define LOG2E 1.44269504088896340736f

typedef __attribute__((ext_vector_type(8))) short short8;
typedef __attribute__((ext_vector_type(4))) float f32x4;
typedef __attribute__((ext_vector_type(16))) float f32x16;

__device__ __forceinline__ unsigned short f2bf(float f) {
  union { float f; uint32_t u; } x; x.f = f;
  uint32_t u = x.u;
  u += 0x7FFFu + ((u >> 16) & 1u);
  return (unsigned short)(u >> 16);
}

__device__ __forceinline__ unsigned int pack_bf(float lo, float hi2) {
  return (unsigned int)f2bf(lo) | ((unsigned int)f2bf(hi2) << 16);
}

__device__ __forceinline__ void gll16(const void* g, void* l) {
  __builtin_amdgcn_global_load_lds(
      (__attribute__((address_space(1))) void*)(g),
      (__attribute__((address_space(3))) void*)(l), 16, 0, 0);
}

// ---- fused prep: hidden f32->bf16 (blocks 0..4095), Wqkv^T (4096..7167),
// ---- Wproj^T (7168..8191) ----
__global__ __launch_bounds__(256) void k_prep(const float* __restrict__ hs,
                                              const float* __restrict__ Wqkv,
                                              const float* __restrict__ Wproj,
                                              unsigned short* __restrict__ hid,
                                              unsigned short* __restrict__ wqkvT,
                                              unsigned short* __restrict__ wprT) {
  __shared__ unsigned short tile[32][33];
  const int id = blockIdx.x;
  if (id < 4096) {
    const int i = id * 256 + threadIdx.x;
    float4 v = reinterpret_cast<const float4*>(hs)[i];
    ushort4 o;
    o.x = f2bf(v.x); o.y = f2bf(v.y); o.z = f2bf(v.z); o.w = f2bf(v.w);
    reinterpret_cast<ushort4*>(hid)[i] = o;
    return;
  }
  const float* W;
  unsigned short* WT;
  int N, i;
  if (id < 7168) { i = id - 4096; W = Wqkv; WT = wqkvT; N = 3072; }
  else           { i = id - 7168; W = Wproj; WT = wprT; N = 1024; }
  const int nb = (N == 3072) ? 96 : 32;
  const int n0 = (i % nb) * 32, k0 = (i / nb) * 32;
  const int tx = threadIdx.x & 31, ty = threadIdx.x >> 5;  // ty 0..7
#pragma unroll
  for (int j = 0; j < 4; j++) {
    int k = ty + j * 8;
    tile[k][tx] = f2bf(W[(long)(k0 + k) * N + n0 + tx]);
  }
  __syncthreads();
#pragma unroll
  for (int j = 0; j < 4; j++) {
    int n = ty + j * 8;
    WT[(long)(n0 + n) * 1024 + k0 + tx] = tile[tx][n];
  }
}

// ---- 128xBN bf16 GEMM, A[M][K], BT[N][K]; MODE 0 = qkv scatter (BN=128),
// ---- MODE 1 = f32 out. BN in {64,128}; warps 2x2 over (128, BN). ----
template <int MODE, int BN>
__global__ __launch_bounds__(256) void k_gemm(
    const unsigned short* __restrict__ A,
    const unsigned short* __restrict__ BT,
    const float* __restrict__ bias,
    void* __restrict__ out0,
    unsigned short* __restrict__ outk,
    unsigned short* __restrict__ outv,
    int M, int N, int K) {
  constexpr int JN = BN / 32;  // 16-col j-tiles per warp
  __shared__ __align__(16) unsigned short lds_a[128 * 32];
  __shared__ __align__(16) unsigned short lds_b[BN * 32];
  const int t = threadIdx.x;
  const int w = t >> 6, l = t & 63;
  const int g = l >> 4, x = l & 15;
  const int wr = w >> 1, wc = w & 1;
  const long m0 = (long)blockIdx.x * 128, n0 = (long)blockIdx.y * BN;

  f32x4 acc[4][JN];
#pragma unroll
  for (int i = 0; i < 4; i++)
#pragma unroll
    for (int j = 0; j < JN; j++) acc[i][j] = (f32x4){0.f, 0.f, 0.f, 0.f};

  const unsigned short* ga = A + (m0 + 16 * w + (l >> 2)) * (long)K + (l & 3) * 8;
  const unsigned short* gb = BT + (n0 + 16 * w + (l >> 2)) * (long)K + (l & 3) * 8;
  unsigned short* la = lds_a + w * 512;
  unsigned short* lb = lds_b + w * 512;

  for (int k0 = 0; k0 < K; k0 += 32) {
    __syncthreads();
    gll16(ga + k0, la);
    gll16(ga + k0 + 64 * (long)K, la + 2048);
    gll16(gb + k0, lb);
    if (BN == 128) gll16(gb + k0 + 64 * (long)K, lb + 2048);
    __syncthreads();
    short8 af[4], bfr[JN];
#pragma unroll
    for (int i = 0; i < 4; i++)
      af[i] = *reinterpret_cast<const short8*>(lds_a + (wr * 64 + i * 16 + x) * 32 + g * 8);
#pragma unroll
    for (int j = 0; j < JN; j++)
      bfr[j] = *reinterpret_cast<const short8*>(
          lds_b + (wc * (BN / 2) + j * 16 + x) * 32 + g * 8);
#pragma unroll
    for (int i = 0; i < 4; i++)
#pragma unroll
      for (int j = 0; j < JN; j++)
        acc[i][j] = __builtin_amdgcn_mfma_f32_16x16x32_bf16(af[i], bfr[j], acc[i][j], 0, 0, 0);
  }

#pragma unroll
  for (int i = 0; i < 4; i++) {
#pragma unroll
    for (int j = 0; j < JN; j++) {
#pragma unroll
      for (int r = 0; r < 4; r++) {
        const long m = m0 + wr * 64 + i * 16 + 4 * g + r;
        const long n = n0 + wc * (BN / 2) + j * 16 + x;
        float v = acc[i][j][r] + bias[n];
        if (MODE == 1) {
          ((float*)out0)[m * N + n] = v;
        } else {
          const int b = (int)(m >> 11), s = (int)(m & 2047);
          const int which = (int)(n >> 10);
          const int rem = (int)(n & 1023);
          const int h = rem >> 6, d = rem & 63;
          const long idx = (((long)(b * H_ + h)) * S_ + s) * DH_ + d;
          unsigned short bv = f2bf(v);
          if (which == 0) ((unsigned short*)out0)[idx] = bv;
          else if (which == 1) outk[idx] = bv;
          else outv[idx] = bv;
        }
      }
    }
  }
}

// ---- V [bh][s][dh] -> VT [bh][dh][s] ----
__global__ __launch_bounds__(256) void k_tr_v(const unsigned short* __restrict__ v,
                                              unsigned short* __restrict__ vt) {
  __shared__ __align__(16) unsigned short tile[64][72];
  const int bh = blockIdx.y;
  const int s0 = blockIdx.x * 64;
  const int t = threadIdx.x;
  const int r = t >> 2;
  const int c = (t & 3) * 16;
  const unsigned short* src = v + ((long)bh * S_ + s0 + r) * DH_ + c;
  *reinterpret_cast<short8*>(&tile[r][c]) = *reinterpret_cast<const short8*>(src);
  *reinterpret_cast<short8*>(&tile[r][c + 8]) = *reinterpret_cast<const short8*>(src + 8);
  __syncthreads();
  unsigned short* dst = vt + ((long)bh * DH_ + r) * S_ + s0 + c;
#pragma unroll
  for (int jj = 0; jj < 2; jj++) {
    short8 o;
#pragma unroll
    for (int j = 0; j < 8; j++) o[j] = (short)tile[c + jj * 8 + j][r];
    *reinterpret_cast<short8*>(dst + jj * 8) = o;
  }
}

// ---- causal flash attention, 32x32 MFMA, swapped QK^T, in-register softmax ----
// Grid: 512 one-chunk blocks (128 q-rows each). Bijective id->(bh,c) swizzle:
// co-resident ids r, r+256 get complementary chunks (c, 15-c) -> 34 total
// kv-steps per CU pair (balance), and each bh's K/V stays on one XCD's L2.
__global__ __launch_bounds__(256, 1) void k_attn(const unsigned short* __restrict__ qb_,
                                                 const unsigned short* __restrict__ kb,
                                                 const unsigned short* __restrict__ vt,
                                                 unsigned short* __restrict__ attn_out) {
  __shared__ __align__(16) unsigned short lds_k[2][4096];
  __shared__ __align__(16) unsigned short lds_v[2][4096];

  const int t0 = threadIdx.x;
  const int w = t0 >> 6, l = t0 & 63;
  const int q32 = l & 31, hi = l >> 5;
  const int r7 = q32 & 7;
  const int lr = l >> 3, sch = (l & 7) ^ lr;  // staging: pre-swizzled source chunk

  const int id = blockIdx.x;
  const int xcd = id & 7, slot = id >> 3;
  const int bh = xcd + 8 * (slot >> 4);
  const int craw = slot & 15;
  const int qc = (slot & 32) ? craw : (15 - craw);

  const int b = bh >> 4, h = bh & 15;
  const long kvbase = (long)bh * S_ * DH_;
  const long vtbase = (long)bh * DH_ * S_;
  const float SC = 0.125f * LOG2E;  // scores kept in log2 domain

  const int q0p = qc * 128;
  const int q0w = q0p + 32 * w;
  const int qg = q0w + q32;
  const int nt = 2 * qc + 2;

  // Q fragments (B-operand): row qg, dh = 16f + 8*hi + j
  short8 qf[4];
#pragma unroll
  for (int f = 0; f < 4; f++)
    qf[f] = *reinterpret_cast<const short8*>(qb_ + kvbase + (long)qg * DH_ + 16 * f + 8 * hi);

  // stage tile 0 into buf 0
#pragma unroll
  for (int i = 0; i < 2; i++) {
    gll16(kb + kvbase + (long)(16 * w + 8 * i + lr) * DH_ + sch * 8,
          &lds_k[0][w * 1024 + i * 512]);
    gll16(vt + vtbase + (long)(16 * w + 8 * i + lr) * S_ + sch * 8,
          &lds_v[0][w * 1024 + i * 512]);
  }

  f32x16 oacc[2];
#pragma unroll
  for (int dt = 0; dt < 2; dt++)
#pragma unroll
    for (int r = 0; r < 16; r++) oacc[dt][r] = 0.f;
  float m = -1.0e30f, lown = 0.f;

  asm volatile("s_waitcnt vmcnt(0)" ::: "memory");
  __syncthreads();

  for (int tt = 0; tt < nt; tt++) {
    const int kv0 = tt * 64;
    // prefetch next tile into other buffer
    if (tt + 1 < nt) {
      const int nb = (tt + 1) & 1;
      const int kvn = kv0 + 64;
#pragma unroll
      for (int i = 0; i < 2; i++) {
        gll16(kb + kvbase + (long)(kvn + 16 * w + 8 * i + lr) * DH_ + sch * 8,
              &lds_k[nb][w * 1024 + i * 512]);
        gll16(vt + vtbase + (long)(16 * w + 8 * i + lr) * S_ + kvn + sch * 8,
              &lds_v[nb][w * 1024 + i * 512]);
      }
    }

    if (kv0 <= q0w + 31) {  // warp has live rows in this tile
      const unsigned short* lk = lds_k[tt & 1];
      const unsigned short* lv = lds_v[tt & 1];

      // QK^T (swapped): sa[ks][reg] = S^T[kv = 32ks + R(reg,hi)][q = q32]
      f32x16 sa[2];
#pragma unroll
      for (int ks = 0; ks < 2; ks++) {
#pragma unroll
        for (int r = 0; r < 16; r++) sa[ks][r] = 0.f;
#pragma unroll
        for (int f = 0; f < 4; f++) {
          short8 kf = *reinterpret_cast<const short8*>(
              lk + (32 * ks + q32) * 64 + (((2 * f + hi) ^ r7) << 3));
          sa[ks] = __builtin_amdgcn_mfma_f32_32x32x16_bf16(kf, qf[f], sa[ks], 0, 0, 0);
        }
      }

      float p[32];
#pragma unroll
      for (int ks = 0; ks < 2; ks++)
#pragma unroll
        for (int r = 0; r < 16; r++) p[16 * ks + r] = sa[ks][r] * SC;

      const bool diag = (kv0 + 63 > q0w);
      if (diag) {
#pragma unroll
        for (int ks = 0; ks < 2; ks++)
#pragma unroll
          for (int r = 0; r < 16; r++) {
            const int kvg = kv0 + 32 * ks + (r & 3) + 8 * (r >> 2) + 4 * hi;
            if (kvg > qg) p[16 * ks + r] = -1.0e30f;
          }
      }

      // tile max (in-lane tree + lane^32 partner)
      float mx[16];
#pragma unroll
      for (int r = 0; r < 16; r++) mx[r] = fmaxf(p[r], p[r + 16]);
#pragma unroll
      for (int st = 8; st >= 1; st >>= 1)
#pragma unroll
        for (int r = 0; r < 8; r++)
          if (r < st) mx[r] = fmaxf(mx[r], mx[r + st]);
      float pmax = fmaxf(mx[0], __shfl_xor(mx[0], 32, 64));

      // defer-max rescale (THR = 8 in log2 domain)
      if (__any(pmax > m + 8.0f)) {
        const float mn = fmaxf(m, pmax);
        const float fsc = exp2f(m - mn);
        m = mn;
        lown *= fsc;
#pragma unroll
        for (int r = 0; r < 16; r++) {
          const int rr = (r & 3) + 8 * (r >> 2) + 4 * hi;
          const float fr = __int_as_float(
              __builtin_amdgcn_ds_bpermute(rr << 2, __float_as_int(fsc)));
          oacc[0][r] *= fr;
          oacc[1][r] *= fr;
        }
      }

      // exp (log2 domain)
#pragma unroll
      for (int i = 0; i < 32; i++) p[i] = exp2f(p[i] - m);

      // own-half row sum (partner combined once at end)
      float sm[16];
#pragma unroll
      for (int r = 0; r < 16; r++) sm[r] = p[r] + p[r + 16];
#pragma unroll
      for (int st = 8; st >= 1; st >>= 1)
#pragma unroll
        for (int r = 0; r < 8; r++)
          if (r < st) sm[r] += sm[r + st];
      lown += sm[0];

      // PV: 4 k-steps of 16 kv. A-word j-pair must hold
      // P[q32][kv = 16*s4 + 8*hi + {2j, 2j+1}]; other half via lane^32.
#pragma unroll
      for (int s4 = 0; s4 < 4; s4++) {
        const int bse = 8 * s4;
        unsigned int t0p = pack_bf(p[bse + 0], p[bse + 1]);
        unsigned int t1p = pack_bf(p[bse + 2], p[bse + 3]);
        unsigned int t2p = pack_bf(p[bse + 4], p[bse + 5]);
        unsigned int t3p = pack_bf(p[bse + 6], p[bse + 7]);
        unsigned int t0x = __shfl_xor(t0p, 32, 64);
        unsigned int t1x = __shfl_xor(t1p, 32, 64);
        unsigned int t2x = __shfl_xor(t2p, 32, 64);
        unsigned int t3x = __shfl_xor(t3p, 32, 64);
        union { unsigned int u[4]; short8 s8; } pa;
        pa.u[0] = hi ? t2x : t0p;  // kv +{0,1}
        pa.u[1] = hi ? t3x : t1p;  // kv +{2,3}
        pa.u[2] = hi ? t2p : t0x;  // kv +{4,5}
        pa.u[3] = hi ? t3p : t1x;  // kv +{6,7}
#pragma unroll
        for (int dt = 0; dt < 2; dt++) {
          short8 vf = *reinterpret_cast<const short8*>(
              lv + (32 * dt + q32) * 64 + (((2 * s4 + hi) ^ r7) << 3));
          oacc[dt] = __builtin_amdgcn_mfma_f32_32x32x16_bf16(pa.s8, vf, oacc[dt], 0, 0, 0);
        }
      }
    }

    asm volatile("s_waitcnt vmcnt(0)" ::: "memory");
    __syncthreads();
  }

  // epilogue: combine partner half, normalize, store
  const float lt = lown + __shfl_xor(lown, 32, 64);
  const float linv = 1.0f / lt;
#pragma unroll
  for (int r = 0; r < 16; r++) {
    const int rr = (r & 3) + 8 * (r >> 2) + 4 * hi;
    const float li = __int_as_float(
        __builtin_amdgcn_ds_bpermute(rr << 2, __float_as_int(linv)));
    const long row = (long)b * S_ + q0w + rr;
#pragma unroll
    for (int dt = 0; dt < 2; dt++)
      attn_out[row * (H_ * DH_) + h * DH_ + 32 * dt + q32] = f2bf(oacc[dt][r] * li);
  }
}

extern "C" void kernel_launch(void* const* d_in, const int* in_sizes, int n_in,
                              void* d_out, int out_size, void* d_ws, size_t ws_size,
                              hipStream_t stream) {
  (void)in_sizes; (void)n_in; (void)out_size; (void)ws_size;
  const float* hs    = (const float*)d_in[0];
  // d_in[1] = attention_mask: deterministic causal tril, applied analytically.
  const float* Wqkv  = (const float*)d_in[2];
  const float* bqkv  = (const float*)d_in[3];
  const float* Wproj = (const float*)d_in[4];
  const float* bproj = (const float*)d_in[5];
  float* out = (float*)d_out;

  unsigned short* ws    = (unsigned short*)d_ws;
  unsigned short* hid   = ws;                 // 4096*1024
  unsigned short* wqkvT = hid + 4194304;      // 3072*1024
  unsigned short* wprT  = wqkvT + 3145728;    // 1024*1024
  unsigned short* q_b   = wprT + 1048576;     // [bh][s][dh]
  unsigned short* k_b   = q_b + 4194304;
  unsigned short* v_b   = k_b + 4194304;
  unsigned short* vt_b  = v_b + 4194304;      // [bh][dh][s]
  unsigned short* ao    = vt_b + 4194304;     // [b*s][H*DH]

  k_prep<<<8192, 256, 0, stream>>>(hs, Wqkv, Wproj, hid, wqkvT, wprT);
  k_gemm<0, 128><<<dim3(32, 24), 256, 0, stream>>>(hid, wqkvT, bqkv, (void*)q_b, k_b, v_b,
                                                   4096, 3072, 1024);
  k_tr_v<<<dim3(32, 32), 256, 0, stream>>>(v_b, vt_b);
  k_attn<<<512, 256, 0, stream>>>(q_b, k_b, vt_b, ao);
  k_gemm<1, 64><<<dim3(32, 16), 256, 0, stream>>>(ao, wprT, bproj, (void*)out, nullptr, nullptr,
                                                  4096, 1024, 1024);
}